// Round 10
// baseline (9847.395 us; speedup 1.0000x reference)
//
#include <hip/hip_runtime.h>
#include <hip/hip_fp16.h>
#include <cstdint>
#include <cstddef>

typedef _Float16 f16x8 __attribute__((ext_vector_type(8)));
typedef float    f32x4 __attribute__((ext_vector_type(4)));

#define MFMA(A,B,C) __builtin_amdgcn_mfma_f32_16x16x32_f16((A),(B),(C),0,0,0)

// ---- problem constants ----
#define NRES  2048
#define DIN   32
#define DOUT  16
#define HDIM  128
#define BBATCH 64
#define TSTEPS 256
#define NBLK  256      // exactly 1 block/CU; block b owns state cols [8b, 8b+8)
#define S16N  (BBATCH * NRES)   // one state buffer, elements

// ---- workspace layout (bytes) ----
#define OFF_WPK   ((size_t)0)          // packed [res8|att8] weights: 4096*2048 f16 = 16,777,216
#define OFF_WH1   ((size_t)16777216)   // 128*2048 f16 -> 17,301,504
#define OFF_BIAS  ((size_t)17301504)   // 4224 f32     -> 17,318,400
#define OFF_WE2H  ((size_t)17318400)   // 128*128 f16  -> 17,351,168
#define OFF_WE3H  ((size_t)17351168)   // 2048*128 f16 -> 17,875,456
#define OFF_S16   ((size_t)17875456)   // 2 x 64*2048 f16 (double buffer) -> 18,399,744
#define OFF_WINH  ((size_t)18399744)   // 2048*32 f16  -> 18,530,816
#define OFF_G2    ((size_t)18530816)   // 64*128 f16   -> 18,547,200
#define OFF_CNT   ((size_t)18547200)   // fg2: 4 lines | slots: 256 lines (64B each)

__device__ __forceinline__ float gelu_exact(float v) {
  return 0.5f * v * (1.0f + erff(v * 0.70710678118654752f));
}

// coalesced 16B write-through store (visible at device coherence point; L2 stays clean)
__device__ __forceinline__ void stg16(void* p, f32x4 v) {
  asm volatile("global_store_dwordx4 %0, %1, off sc0 sc1" :: "v"(p), "v"(v) : "memory");
}

// ---------------- prep kernels (verified R8/R9) ----------------

__global__ void k_cast(const float* __restrict__ src, _Float16* __restrict__ dst, int n) {
  int i = blockIdx.x * blockDim.x + threadIdx.x;
  int stride = gridDim.x * blockDim.x;
  for (; i < n; i += stride) dst[i] = (_Float16)src[i];
}

// W_res col c -> packed row (c>>3)*16 + (c&7)
__global__ void k_castres(const float* __restrict__ W_res, _Float16* __restrict__ wpk) {
  int c = blockIdx.x, k0 = threadIdx.x * 8;
  int pr = (c >> 3) * 16 + (c & 7);
  const float* s = &W_res[(size_t)c * NRES + k0];
  _Float16* d = &wpk[(size_t)pr * NRES + k0];
  #pragma unroll
  for (int j = 0; j < 8; ++j) d[j] = (_Float16)s[j];
}

__global__ void k_batt(const float* __restrict__ Wproj, const float* __restrict__ bv,
                       const float* __restrict__ bproj, float* __restrict__ bias_big) {
  int c = blockIdx.x, tid = threadIdx.x;
  float p = 0.f;
  for (int k = tid; k < NRES; k += 256) p += Wproj[(size_t)c * NRES + k] * bv[k];
  for (int m = 1; m < 64; m <<= 1) p += __shfl_xor(p, m);
  __shared__ float r4[4];
  if ((tid & 63) == 0) r4[tid >> 6] = p;
  __syncthreads();
  if (tid == 0) bias_big[2048 + c] = r4[0] + r4[1] + r4[2] + r4[3] + bproj[c];
}

__global__ void k_bh1(const float* __restrict__ We1, const float* __restrict__ be1,
                      float* __restrict__ bias_big) {
  int h = blockIdx.x, tid = threadIdx.x;
  float p = 0.f;
  for (int n = tid; n < NRES; n += 256) p += We1[(size_t)h * NRES + n] * bias_big[2048 + n];
  for (int m = 1; m < 64; m <<= 1) p += __shfl_xor(p, m);
  __shared__ float r4[4];
  if ((tid & 63) == 0) r4[tid >> 6] = p;
  __syncthreads();
  if (tid == 0) bias_big[4096 + h] = r4[0] + r4[1] + r4[2] + r4[3] + be1[h];
}

// W_att = Wproj @ Wv ; att col c -> packed row (c>>3)*16 + 8 + (c&7)
__global__ void __launch_bounds__(256) k_gemm1(const float* __restrict__ Wproj,
                                               const float* __restrict__ Wv,
                                               _Float16* __restrict__ wpk) {
  __shared__ _Float16 BT[64][40];
  const int kblock = blockIdx.x, cblock = blockIdx.y;
  const int tid = threadIdx.x, wv = tid >> 6, lane = tid & 63;
  const int l4 = lane >> 4, l15 = lane & 15;
  const int crow0 = cblock * 64 + wv * 16;
  f32x4 acc[4];
  f32x4 zero = {0.f, 0.f, 0.f, 0.f};
  for (int i = 0; i < 4; ++i) acc[i] = zero;

  for (int mc = 0; mc < 64; ++mc) {
    const int m0 = mc * 32;
    {
      int m = tid >> 3, kk = (tid & 7) * 8;
      const float* src = &Wv[(size_t)(m0 + m) * NRES + kblock * 64 + kk];
      float4 v0 = *(const float4*)src;
      float4 v1 = *(const float4*)(src + 4);
      float tmp[8] = {v0.x, v0.y, v0.z, v0.w, v1.x, v1.y, v1.z, v1.w};
      #pragma unroll
      for (int j = 0; j < 8; ++j) BT[kk + j][m] = (_Float16)tmp[j];
    }
    __syncthreads();
    const float* pa = &Wproj[(size_t)(crow0 + l15) * NRES + m0 + l4 * 8];
    float4 a0 = *(const float4*)pa;
    float4 a1 = *(const float4*)(pa + 4);
    f16x8 af;
    af[0]=(_Float16)a0.x; af[1]=(_Float16)a0.y; af[2]=(_Float16)a0.z; af[3]=(_Float16)a0.w;
    af[4]=(_Float16)a1.x; af[5]=(_Float16)a1.y; af[6]=(_Float16)a1.z; af[7]=(_Float16)a1.w;
    #pragma unroll
    for (int kt = 0; kt < 4; ++kt) {
      f16x8 bf = *(const f16x8*)&BT[kt * 16 + l15][l4 * 8];
      acc[kt] = MFMA(af, bf, acc[kt]);
    }
    __syncthreads();
  }
  #pragma unroll
  for (int kt = 0; kt < 4; ++kt)
    #pragma unroll
    for (int i = 0; i < 4; ++i) {
      int c = crow0 + l4 * 4 + i;
      int k = kblock * 64 + kt * 16 + l15;
      int pr = (c >> 3) * 16 + 8 + (c & 7);
      wpk[(size_t)pr * NRES + k] = (_Float16)acc[kt][i];
    }
}

// W_h1 = We1 @ W_att (att rows read from packed layout) -> wh1[128][2048]
__global__ void __launch_bounds__(256) k_gemm2(const float* __restrict__ We1,
                                               const _Float16* __restrict__ wpk,
                                               _Float16* __restrict__ wh1) {
  __shared__ _Float16 BT[64][40];
  const int kblock = blockIdx.x, hblock = blockIdx.y;
  const int tid = threadIdx.x, wv = tid >> 6, lane = tid & 63;
  const int l4 = lane >> 4, l15 = lane & 15;
  const int hrow0 = hblock * 64 + wv * 16;
  f32x4 acc[4];
  f32x4 zero = {0.f, 0.f, 0.f, 0.f};
  for (int i = 0; i < 4; ++i) acc[i] = zero;

  for (int nc = 0; nc < 64; ++nc) {
    const int n0 = nc * 32;
    {
      int n = tid >> 3, kk = (tid & 7) * 8;
      int nn = n0 + n;
      int pr = (nn >> 3) * 16 + 8 + (nn & 7);
      f16x8 v = *(const f16x8*)&wpk[(size_t)pr * NRES + kblock * 64 + kk];
      #pragma unroll
      for (int j = 0; j < 8; ++j) BT[kk + j][n] = v[j];
    }
    __syncthreads();
    const float* pa = &We1[(size_t)(hrow0 + l15) * NRES + n0 + l4 * 8];
    float4 a0 = *(const float4*)pa;
    float4 a1 = *(const float4*)(pa + 4);
    f16x8 af;
    af[0]=(_Float16)a0.x; af[1]=(_Float16)a0.y; af[2]=(_Float16)a0.z; af[3]=(_Float16)a0.w;
    af[4]=(_Float16)a1.x; af[5]=(_Float16)a1.y; af[6]=(_Float16)a1.z; af[7]=(_Float16)a1.w;
    #pragma unroll
    for (int kt = 0; kt < 4; ++kt) {
      f16x8 bf = *(const f16x8*)&BT[kt * 16 + l15][l4 * 8];
      acc[kt] = MFMA(af, bf, acc[kt]);
    }
    __syncthreads();
  }
  #pragma unroll
  for (int kt = 0; kt < 4; ++kt)
    #pragma unroll
    for (int i = 0; i < 4; ++i) {
      int h = hrow0 + l4 * 4 + i;
      int k = kblock * 64 + kt * 16 + l15;
      wh1[(size_t)h * NRES + k] = (_Float16)acc[kt][i];
    }
}

// ---------------- all-poll-all barrier (no collector; 1 serial fabric hop) ----------------
// slots: 256 private 64B lines. Thread i polls slot i; block-wide AND via __syncthreads_and.
__device__ __forceinline__ void gbar4(unsigned* slots, int b, unsigned phase) {
  asm volatile("s_waitcnt vmcnt(0)" ::: "memory");   // sc1 stores acked at coherence point
  __syncthreads();
  if (threadIdx.x == 0)
    __hip_atomic_store(slots + (size_t)b * 16, phase, __ATOMIC_RELAXED, __HIP_MEMORY_SCOPE_AGENT);
  unsigned spins = 0;
  for (;;) {
    unsigned v = __hip_atomic_load(slots + (size_t)threadIdx.x * 16,
                                   __ATOMIC_RELAXED, __HIP_MEMORY_SCOPE_AGENT);
    if (__syncthreads_and((int)(v >= phase))) break;
    if (++spins > (1u << 18)) break;   // safety bail: wrong answer, not hang
    __builtin_amdgcn_s_sleep(2);
  }
  if (threadIdx.x == 0)
    (void)__hip_atomic_load(slots, __ATOMIC_ACQUIRE, __HIP_MEMORY_SCOPE_AGENT);  // L1/L2 inv
  __syncthreads();
}

// ---------------- main persistent kernel ----------------

__global__ void __launch_bounds__(256, 2) k_main(
    const float* __restrict__ x,
    const float* __restrict__ ln_g, const float* __restrict__ ln_b,
    const float* __restrict__ be2v, const float* __restrict__ be3v,
    const float* __restrict__ w_mu, const float* __restrict__ w_rho,
    const float* __restrict__ b_mu, const float* __restrict__ b_rho,
    const float* __restrict__ w_eps, const float* __restrict__ b_eps,
    const _Float16* __restrict__ wpk, const _Float16* __restrict__ wh1,
    const float* __restrict__ bias_big,
    const _Float16* __restrict__ we2h, const _Float16* __restrict__ we3h,
    const _Float16* __restrict__ winh,
    _Float16* s16, _Float16* g2buf,
    unsigned* cnt, float* __restrict__ out)
{
  const int b = blockIdx.x, tid = threadIdx.x;
  unsigned* fg2   = cnt;          // 4 flags, one 64B line each (stride 16 u32)
  unsigned* slots = cnt + 64;     // 256 lines, stride 16 u32

  const int wv = tid >> 6, lane = tid & 63;
  const int l4 = lane >> 4, l15 = lane & 15;

  __shared__ float    lds_red[4][64][17];   // K-split reduce (S1 and h-duty)
  __shared__ _Float16 lds_w2[128][136];     // We2 resident
  __shared__ _Float16 lds_h1[16][136];      // h-duty: gelu(LN(h1)) then g2 bounce
  __shared__ _Float16 lds_x[64][40];        // x_t all 64 rows (f16)
  __shared__ _Float16 lds_ns[64][16];       // new-state bounce (8 cols + pad)

  const bool hduty = (b < 4);
  const int  hrt   = b;                     // h-duty row-tile (rows 16b..16b+15)

  // ---- S1 weights: packed [res8|att8] for cols 8b..8b+8, full K in VGPRs ----
  f16x8 Bf[16];
  #pragma unroll
  for (int ks = 0; ks < 16; ++ks)
    Bf[ks] = *(const f16x8*)&wpk[(size_t)(b * 16 + l15) * NRES + wv * 512 + ks * 32 + l4 * 8];

  // ---- update-phase constants (cols 8b + l15, valid for l15 < 8) ----
  const int mycol = 8 * b + (l15 & 7);
  const bool colv = (l15 < 8);
  f16x8 zf;
  #pragma unroll
  for (int j = 0; j < 8; ++j) zf[j] = (_Float16)0.f;
  f16x8 We3f[4];
  f16x8 Winf = zf;
  if (colv) {
    #pragma unroll
    for (int ks = 0; ks < 4; ++ks)
      We3f[ks] = *(const f16x8*)&we3h[(size_t)mycol * HDIM + ks * 32 + l4 * 8];
    Winf = *(const f16x8*)&winh[(size_t)mycol * DIN + l4 * 8];
  } else {
    #pragma unroll
    for (int ks = 0; ks < 4; ++ks) We3f[ks] = zf;
  }
  const float be3r  = colv ? be3v[mycol] : 0.f;
  const float battr = colv ? bias_big[2048 + mycol] : 0.f;

  // ---- h-duty constants ----
  float g8[8], bb8[8], bh8[8];
  #pragma unroll
  for (int ct = 0; ct < 8; ++ct) {
    g8[ct]  = ln_g[ct * 16 + l15];
    bb8[ct] = ln_b[ct * 16 + l15];
    bh8[ct] = bias_big[4096 + ct * 16 + l15];
  }
  float be2r[2];
  #pragma unroll
  for (int ct = 0; ct < 2; ++ct) be2r[ct] = be2v[(wv * 2 + ct) * 16 + l15];

  { // stage We2 into LDS once
    int row = tid >> 1, half = tid & 1;
    #pragma unroll
    for (int j = 0; j < 8; ++j)
      *(f16x8*)&lds_w2[row][half * 64 + j * 8] =
          *(const f16x8*)&we2h[(size_t)row * HDIM + half * 64 + j * 8];
  }
  __syncthreads();

  const f32x4 zero = {0.f, 0.f, 0.f, 0.f};
  const int laneR = (l4 << 4) | (l15 & 7);   // rrv source lane in lds_red
  const int laneA = laneR + 8;               // satt source lane

  for (int t = 0; t < TSTEPS; ++t) {
    // double-buffered state: read buf[t&1], write buf[(t+1)&1]
    const _Float16* sread = s16 + (size_t)(t & 1) * S16N;
    _Float16* swrite      = s16 + (size_t)((t + 1) & 1) * S16N;

    // ========== h-duty FIRST: h1 -> LN -> GELU -> We2 -> GELU -> publish g2 ==========
    if (hduty) {
      f32x4 hacc[8];
      #pragma unroll
      for (int ct = 0; ct < 8; ++ct) hacc[ct] = zero;
      for (int kc = 0; kc < 16; ++kc) {
        f16x8 Ah = *(const f16x8*)&sread[(size_t)(hrt * 16 + l15) * NRES + wv * 512 + kc * 32 + l4 * 8];
        #pragma unroll
        for (int ct = 0; ct < 8; ++ct) {
          f16x8 Bh = *(const f16x8*)&wh1[(size_t)(ct * 16 + l15) * NRES + wv * 512 + kc * 32 + l4 * 8];
          hacc[ct] = MFMA(Ah, Bh, hacc[ct]);
        }
      }
      // 2-pass K-reduce across waves via lds_red
      float hv[32];
      #pragma unroll
      for (int ct = 0; ct < 4; ++ct)
        #pragma unroll
        for (int i = 0; i < 4; ++i) lds_red[wv][lane][ct * 4 + i] = hacc[ct][i];
      __syncthreads();
      #pragma unroll
      for (int ct = 0; ct < 4; ++ct)
        #pragma unroll
        for (int i = 0; i < 4; ++i)
          hv[ct * 4 + i] = lds_red[0][lane][ct * 4 + i] + lds_red[1][lane][ct * 4 + i]
                         + lds_red[2][lane][ct * 4 + i] + lds_red[3][lane][ct * 4 + i];
      __syncthreads();
      #pragma unroll
      for (int ct = 0; ct < 4; ++ct)
        #pragma unroll
        for (int i = 0; i < 4; ++i) lds_red[wv][lane][ct * 4 + i] = hacc[4 + ct][i];
      __syncthreads();
      #pragma unroll
      for (int ct = 4; ct < 8; ++ct)
        #pragma unroll
        for (int i = 0; i < 4; ++i)
          hv[ct * 4 + i] = lds_red[0][lane][(ct - 4) * 4 + i] + lds_red[1][lane][(ct - 4) * 4 + i]
                         + lds_red[2][lane][(ct - 4) * 4 + i] + lds_red[3][lane][(ct - 4) * 4 + i];
      __syncthreads();
      // bias + LayerNorm per row (rows l4*4+i; 128 cols = 8 ct x 16 l15)
      float s1v[4] = {0.f, 0.f, 0.f, 0.f}, s2v[4] = {0.f, 0.f, 0.f, 0.f};
      #pragma unroll
      for (int ct = 0; ct < 8; ++ct)
        #pragma unroll
        for (int i = 0; i < 4; ++i) {
          float v = hv[ct * 4 + i] + bh8[ct];
          hv[ct * 4 + i] = v; s1v[i] += v; s2v[i] += v * v;
        }
      #pragma unroll
      for (int m = 1; m < 16; m <<= 1)
        #pragma unroll
        for (int i = 0; i < 4; ++i) { s1v[i] += __shfl_xor(s1v[i], m); s2v[i] += __shfl_xor(s2v[i], m); }
      #pragma unroll
      for (int i = 0; i < 4; ++i) {
        float mu = s1v[i] * (1.f / 128.f);
        float var = s2v[i] * (1.f / 128.f) - mu * mu;
        float rs = rsqrtf(var + 1e-5f);
        if (wv == 0) {
          #pragma unroll
          for (int ct = 0; ct < 8; ++ct) {
            float hn = (hv[ct * 4 + i] - mu) * rs * g8[ct] + bb8[ct];
            lds_h1[l4 * 4 + i][ct * 16 + l15] = (_Float16)gelu_exact(hn);
          }
        }
      }
      __syncthreads();
      // h2 = gelu(h1g @ We2^T + be2): wave wv does col-tiles wv*2, wv*2+1
      f32x4 c0 = zero, c1 = zero;
      #pragma unroll
      for (int ks = 0; ks < 4; ++ks) {
        f16x8 af = *(const f16x8*)&lds_h1[l15][ks * 32 + l4 * 8];
        f16x8 b0 = *(const f16x8*)&lds_w2[(wv * 2 + 0) * 16 + l15][ks * 32 + l4 * 8];
        f16x8 b1 = *(const f16x8*)&lds_w2[(wv * 2 + 1) * 16 + l15][ks * 32 + l4 * 8];
        c0 = MFMA(af, b0, c0);
        c1 = MFMA(af, b1, c1);
      }
      __syncthreads();   // MFMA reads of lds_h1 done; reuse as g2 bounce
      #pragma unroll
      for (int i = 0; i < 4; ++i) {
        int rr = l4 * 4 + i;
        lds_h1[rr][(wv * 2 + 0) * 16 + l15] = (_Float16)gelu_exact(c0[i] + be2r[0]);
        lds_h1[rr][(wv * 2 + 1) * 16 + l15] = (_Float16)gelu_exact(c1[i] + be2r[1]);
      }
      __syncthreads();
      { // publish g2 tile (16 rows x 128) with 16B write-through stores
        int row = tid >> 4, ch = tid & 15;
        f16x8 v = *(const f16x8*)&lds_h1[row][ch * 8];
        stg16(&g2buf[(size_t)(hrt * 16 + row) * HDIM + ch * 8], __builtin_bit_cast(f32x4, v));
      }
      asm volatile("s_waitcnt vmcnt(0)" ::: "memory");
      __syncthreads();
      if (tid == 0)
        __hip_atomic_store(fg2 + (size_t)hrt * 16, (unsigned)(t + 1),
                           __ATOMIC_RELAXED, __HIP_MEMORY_SCOPE_AGENT);
    }

    // ========== S1 main (uniform, all blocks): [rrv|satt] partials in LDS ==========
    f32x4 a0 = zero, a1 = zero, a2 = zero, a3 = zero;
    #pragma unroll
    for (int ks = 0; ks < 16; ++ks) {
      const int kk = wv * 512 + ks * 32 + l4 * 8;
      f16x8 A0 = *(const f16x8*)&sread[(size_t)(l15) * NRES + kk];
      f16x8 A1 = *(const f16x8*)&sread[(size_t)(16 + l15) * NRES + kk];
      f16x8 A2 = *(const f16x8*)&sread[(size_t)(32 + l15) * NRES + kk];
      f16x8 A3 = *(const f16x8*)&sread[(size_t)(48 + l15) * NRES + kk];
      a0 = MFMA(A0, Bf[ks], a0);
      a1 = MFMA(A1, Bf[ks], a1);
      a2 = MFMA(A2, Bf[ks], a2);
      a3 = MFMA(A3, Bf[ks], a3);
    }
    __syncthreads();   // h-duty lds_red traffic fully done before overwrite
    #pragma unroll
    for (int i = 0; i < 4; ++i) {
      lds_red[wv][lane][0 + i]  = a0[i];
      lds_red[wv][lane][4 + i]  = a1[i];
      lds_red[wv][lane][8 + i]  = a2[i];
      lds_red[wv][lane][12 + i] = a3[i];
    }
    { // stage x_t: all 64 rows x 32 (f16)
      int row = tid >> 2, k0 = (tid & 3) * 8;
      const float* xs = &x[((size_t)row * TSTEPS + t) * DIN + k0];
      float4 v0 = *(const float4*)xs;
      float4 v1 = *(const float4*)(xs + 4);
      _Float16* d = &lds_x[row][k0];
      d[0]=(_Float16)v0.x; d[1]=(_Float16)v0.y; d[2]=(_Float16)v0.z; d[3]=(_Float16)v0.w;
      d[4]=(_Float16)v1.x; d[5]=(_Float16)v1.y; d[6]=(_Float16)v1.z; d[7]=(_Float16)v1.w;
    }
    // ========== wait for g2 flags (all-threads, overlapped with S1 above) ==========
    {
      unsigned spins = 0;
      for (;;) {
        bool ok = true;
        if (tid < 4) {
          unsigned v = __hip_atomic_load(fg2 + (size_t)tid * 16,
                                         __ATOMIC_RELAXED, __HIP_MEMORY_SCOPE_AGENT);
          ok = (v >= (unsigned)(t + 1));
        }
        if (__syncthreads_and((int)ok)) break;
        if (++spins > (1u << 18)) break;
        __builtin_amdgcn_s_sleep(2);
      }
      if (tid == 0)
        (void)__hip_atomic_load(fg2, __ATOMIC_ACQUIRE, __HIP_MEMORY_SCOPE_AGENT);  // L1/L2 inv
      __syncthreads();
    }

    // ========== update: phys + input + [rrv|satt] -> new state (wave wv: rows wv*16..+15) ==========
    {
      f32x4 accp = zero;
      #pragma unroll
      for (int kc = 0; kc < 4; ++kc) {
        f16x8 ag = *(const f16x8*)&g2buf[(size_t)(wv * 16 + l15) * HDIM + kc * 32 + l4 * 8];
        accp = MFMA(ag, We3f[kc], accp);
      }
      f16x8 ax = *(const f16x8*)&lds_x[wv * 16 + l15][l4 * 8];
      f32x4 acci = MFMA(ax, Winf, zero);
      #pragma unroll
      for (int i = 0; i < 4; ++i) {
        float rr = lds_red[0][laneR][wv * 4 + i] + lds_red[1][laneR][wv * 4 + i]
                 + lds_red[2][laneR][wv * 4 + i] + lds_red[3][laneR][wv * 4 + i];
        float sa = lds_red[0][laneA][wv * 4 + i] + lds_red[1][laneA][wv * 4 + i]
                 + lds_red[2][laneA][wv * 4 + i] + lds_red[3][laneA][wv * 4 + i];
        float ns = 0.7f * (sa + battr) + 0.3f * tanhf(acci[i] + rr + accp[i] + be3r);
        if (colv) lds_ns[wv * 16 + l4 * 4 + i][l15] = (_Float16)ns;
      }
    }
    __syncthreads();
    if (tid < 64) {  // coalesced state store to the WRITE buffer: 64 rows x 16B
      f16x8 v = *(const f16x8*)&lds_ns[tid][0];
      stg16(&swrite[(size_t)tid * NRES + 8 * b], __builtin_bit_cast(f32x4, v));
    }

    // ========== single global barrier per step (all-poll-all) ==========
    gbar4(slots, b, (unsigned)(t + 1));
  }

  // ---- Bayesian output head (blocks 0..63, post final barrier+acquire) ----
  // final state = buffer written at t=255 -> buf index (255+1)&1 = 0 -> s16 base
  if (b < BBATCH) {
    float* red = &lds_red[0][0][0];
    int o = tid >> 4, sg = tid & 15;
    float p = 0.f;
    for (int n = sg * 128; n < sg * 128 + 128; ++n) {
      float sv = (float)s16[(size_t)b * NRES + n];
      float w = w_mu[(size_t)o * NRES + n]
              + log1pf(expf(w_rho[(size_t)o * NRES + n])) * w_eps[(size_t)o * NRES + n];
      p += sv * w;
    }
    red[o * 17 + sg] = p;
    __syncthreads();
    if (tid < DOUT) {
      float sum = 0.f;
      for (int q = 0; q < 16; ++q) sum += red[tid * 17 + q];
      float bs = b_mu[tid] + log1pf(expf(b_rho[tid])) * b_eps[tid];
      out[b * DOUT + tid] = sum + bs;
    }
  }
}

// ---------------- host ----------------

extern "C" void kernel_launch(void* const* d_in, const int* in_sizes, int n_in,
                              void* d_out, int out_size, void* d_ws, size_t ws_size,
                              hipStream_t stream) {
  (void)in_sizes; (void)n_in; (void)out_size; (void)ws_size;
  const float* x     = (const float*)d_in[0];
  const float* W_in  = (const float*)d_in[1];
  const float* W_res = (const float*)d_in[2];
  const float* Wv    = (const float*)d_in[3];
  const float* bv    = (const float*)d_in[4];
  const float* Wproj = (const float*)d_in[5];
  const float* bproj = (const float*)d_in[6];
  const float* We1   = (const float*)d_in[7];
  const float* be1   = (const float*)d_in[8];
  const float* ln_g  = (const float*)d_in[9];
  const float* ln_b  = (const float*)d_in[10];
  const float* We2   = (const float*)d_in[11];
  const float* be2   = (const float*)d_in[12];
  const float* We3   = (const float*)d_in[13];
  const float* be3   = (const float*)d_in[14];
  const float* w_mu  = (const float*)d_in[15];
  const float* w_rho = (const float*)d_in[16];
  const float* b_mu  = (const float*)d_in[17];
  const float* b_rho = (const float*)d_in[18];
  const float* w_eps = (const float*)d_in[19];
  const float* b_eps = (const float*)d_in[20];
  float* out = (float*)d_out;

  char* ws = (char*)d_ws;
  _Float16* wpk      = (_Float16*)(ws + OFF_WPK);
  _Float16* wh1      = (_Float16*)(ws + OFF_WH1);
  float*    bias_big = (float*)(ws + OFF_BIAS);
  _Float16* we2h     = (_Float16*)(ws + OFF_WE2H);
  _Float16* we3h     = (_Float16*)(ws + OFF_WE3H);
  _Float16* s16      = (_Float16*)(ws + OFF_S16);
  _Float16* winh     = (_Float16*)(ws + OFF_WINH);
  _Float16* g2buf    = (_Float16*)(ws + OFF_G2);
  unsigned* cnt      = (unsigned*)(ws + OFF_CNT);

  hipMemsetAsync(bias_big, 0, 4224 * sizeof(float), stream);
  hipMemsetAsync(s16, 0, 2 * (size_t)S16N * sizeof(_Float16), stream);  // both state buffers
  hipMemsetAsync(cnt, 0, (64 + 4096) * 4, stream);   // fg2 lines + slot lines

  k_castres<<<2048, 256, 0, stream>>>(W_res, wpk);                 // res -> packed rows
  k_cast<<<64,   256, 0, stream>>>(We2, we2h, HDIM * HDIM);
  k_cast<<<1024, 256, 0, stream>>>(We3, we3h, NRES * HDIM);
  k_cast<<<256,  256, 0, stream>>>(W_in, winh, NRES * DIN);
  k_batt<<<NRES, 256, 0, stream>>>(Wproj, bv, bproj, bias_big);
  k_gemm1<<<dim3(32, 32), 256, 0, stream>>>(Wproj, Wv, wpk);       // att -> packed rows
  k_bh1<<<HDIM, 256, 0, stream>>>(We1, be1, bias_big);
  k_gemm2<<<dim3(32, 2), 256, 0, stream>>>(We1, wpk, wh1);         // wh1[128][2048]

  k_main<<<NBLK, 256, 0, stream>>>(x, ln_g, ln_b, be2, be3,
                                   w_mu, w_rho, b_mu, b_rho, w_eps, b_eps,
                                   wpk, wh1, bias_big, we2h, we3h, winh,
                                   s16, g2buf, cnt, out);
}

// Round 11
// 9122.286 us; speedup vs baseline: 1.0795x; 1.0795x over previous
//
#include <hip/hip_runtime.h>
#include <hip/hip_fp16.h>
#include <cstdint>
#include <cstddef>

typedef _Float16 f16x8 __attribute__((ext_vector_type(8)));
typedef float    f32x4 __attribute__((ext_vector_type(4)));

#define MFMA(A,B,C) __builtin_amdgcn_mfma_f32_16x16x32_f16((A),(B),(C),0,0,0)

// ---- problem constants ----
#define NRES  2048
#define DIN   32
#define DOUT  16
#define HDIM  128
#define BBATCH 64
#define TSTEPS 256
#define NBLK  256      // 1 block/CU; block b owns state cols [8b, 8b+8)
#define S16N  (BBATCH * NRES)   // one state buffer, elements
#define RING  64       // ring depth: 64 steps x ~272KB/XCD fresh traffic >> 4MB L2 => guaranteed eviction
#define G2N   (BBATCH * HDIM)

// ---- workspace layout (bytes) ----
#define OFF_WPK   ((size_t)0)          // packed [res8|att8] weights: 4096*2048 f16 = 16,777,216
#define OFF_WH1   ((size_t)16777216)   // 128*2048 f16 -> 17,301,504
#define OFF_BIAS  ((size_t)17301504)   // 4224 f32     -> 17,318,400
#define OFF_WE2H  ((size_t)17318400)   // 128*128 f16  -> 17,351,168
#define OFF_WE3H  ((size_t)17351168)   // 2048*128 f16 -> 17,875,456
#define OFF_WINH  ((size_t)17875456)   // 2048*32 f16  -> 18,006,528
#define OFF_G2    ((size_t)18006528)   // RING x 64*128 f16 = 1,048,576 -> 19,055,104
#define OFF_CNT   ((size_t)19055104)   // fg2: 4 lines + slots: 256 lines -> 19,071,744
#define OFF_S16   ((size_t)19072000)   // RING x 64*2048 f16 = 16,777,216 -> 35,849,216

__device__ __forceinline__ float gelu_exact(float v) {
  return 0.5f * v * (1.0f + erff(v * 0.70710678118654752f));
}

// coalesced 16B write-through store (visible at device coherence point; L2 stays clean)
__device__ __forceinline__ void stg16(void* p, f32x4 v) {
  asm volatile("global_store_dwordx4 %0, %1, off sc0 sc1" :: "v"(p), "v"(v) : "memory");
}

// ---------------- prep kernels (verified R8-R10) ----------------

__global__ void k_cast(const float* __restrict__ src, _Float16* __restrict__ dst, int n) {
  int i = blockIdx.x * blockDim.x + threadIdx.x;
  int stride = gridDim.x * blockDim.x;
  for (; i < n; i += stride) dst[i] = (_Float16)src[i];
}

// W_res col c -> packed row (c>>3)*16 + (c&7)
__global__ void k_castres(const float* __restrict__ W_res, _Float16* __restrict__ wpk) {
  int c = blockIdx.x, k0 = threadIdx.x * 8;
  int pr = (c >> 3) * 16 + (c & 7);
  const float* s = &W_res[(size_t)c * NRES + k0];
  _Float16* d = &wpk[(size_t)pr * NRES + k0];
  #pragma unroll
  for (int j = 0; j < 8; ++j) d[j] = (_Float16)s[j];
}

__global__ void k_batt(const float* __restrict__ Wproj, const float* __restrict__ bv,
                       const float* __restrict__ bproj, float* __restrict__ bias_big) {
  int c = blockIdx.x, tid = threadIdx.x;
  float p = 0.f;
  for (int k = tid; k < NRES; k += 256) p += Wproj[(size_t)c * NRES + k] * bv[k];
  for (int m = 1; m < 64; m <<= 1) p += __shfl_xor(p, m);
  __shared__ float r4[4];
  if ((tid & 63) == 0) r4[tid >> 6] = p;
  __syncthreads();
  if (tid == 0) bias_big[2048 + c] = r4[0] + r4[1] + r4[2] + r4[3] + bproj[c];
}

__global__ void k_bh1(const float* __restrict__ We1, const float* __restrict__ be1,
                      float* __restrict__ bias_big) {
  int h = blockIdx.x, tid = threadIdx.x;
  float p = 0.f;
  for (int n = tid; n < NRES; n += 256) p += We1[(size_t)h * NRES + n] * bias_big[2048 + n];
  for (int m = 1; m < 64; m <<= 1) p += __shfl_xor(p, m);
  __shared__ float r4[4];
  if ((tid & 63) == 0) r4[tid >> 6] = p;
  __syncthreads();
  if (tid == 0) bias_big[4096 + h] = r4[0] + r4[1] + r4[2] + r4[3] + be1[h];
}

// W_att = Wproj @ Wv ; att col c -> packed row (c>>3)*16 + 8 + (c&7)
__global__ void __launch_bounds__(256) k_gemm1(const float* __restrict__ Wproj,
                                               const float* __restrict__ Wv,
                                               _Float16* __restrict__ wpk) {
  __shared__ _Float16 BT[64][40];
  const int kblock = blockIdx.x, cblock = blockIdx.y;
  const int tid = threadIdx.x, wv = tid >> 6, lane = tid & 63;
  const int l4 = lane >> 4, l15 = lane & 15;
  const int crow0 = cblock * 64 + wv * 16;
  f32x4 acc[4];
  f32x4 zero = {0.f, 0.f, 0.f, 0.f};
  for (int i = 0; i < 4; ++i) acc[i] = zero;

  for (int mc = 0; mc < 64; ++mc) {
    const int m0 = mc * 32;
    {
      int m = tid >> 3, kk = (tid & 7) * 8;
      const float* src = &Wv[(size_t)(m0 + m) * NRES + kblock * 64 + kk];
      float4 v0 = *(const float4*)src;
      float4 v1 = *(const float4*)(src + 4);
      float tmp[8] = {v0.x, v0.y, v0.z, v0.w, v1.x, v1.y, v1.z, v1.w};
      #pragma unroll
      for (int j = 0; j < 8; ++j) BT[kk + j][m] = (_Float16)tmp[j];
    }
    __syncthreads();
    const float* pa = &Wproj[(size_t)(crow0 + l15) * NRES + m0 + l4 * 8];
    float4 a0 = *(const float4*)pa;
    float4 a1 = *(const float4*)(pa + 4);
    f16x8 af;
    af[0]=(_Float16)a0.x; af[1]=(_Float16)a0.y; af[2]=(_Float16)a0.z; af[3]=(_Float16)a0.w;
    af[4]=(_Float16)a1.x; af[5]=(_Float16)a1.y; af[6]=(_Float16)a1.z; af[7]=(_Float16)a1.w;
    #pragma unroll
    for (int kt = 0; kt < 4; ++kt) {
      f16x8 bf = *(const f16x8*)&BT[kt * 16 + l15][l4 * 8];
      acc[kt] = MFMA(af, bf, acc[kt]);
    }
    __syncthreads();
  }
  #pragma unroll
  for (int kt = 0; kt < 4; ++kt)
    #pragma unroll
    for (int i = 0; i < 4; ++i) {
      int c = crow0 + l4 * 4 + i;
      int k = kblock * 64 + kt * 16 + l15;
      int pr = (c >> 3) * 16 + 8 + (c & 7);
      wpk[(size_t)pr * NRES + k] = (_Float16)acc[kt][i];
    }
}

// W_h1 = We1 @ W_att (att rows read from packed layout) -> wh1[128][2048]
__global__ void __launch_bounds__(256) k_gemm2(const float* __restrict__ We1,
                                               const _Float16* __restrict__ wpk,
                                               _Float16* __restrict__ wh1) {
  __shared__ _Float16 BT[64][40];
  const int kblock = blockIdx.x, hblock = blockIdx.y;
  const int tid = threadIdx.x, wv = tid >> 6, lane = tid & 63;
  const int l4 = lane >> 4, l15 = lane & 15;
  const int hrow0 = hblock * 64 + wv * 16;
  f32x4 acc[4];
  f32x4 zero = {0.f, 0.f, 0.f, 0.f};
  for (int i = 0; i < 4; ++i) acc[i] = zero;

  for (int nc = 0; nc < 64; ++nc) {
    const int n0 = nc * 32;
    {
      int n = tid >> 3, kk = (tid & 7) * 8;
      int nn = n0 + n;
      int pr = (nn >> 3) * 16 + 8 + (nn & 7);
      f16x8 v = *(const f16x8*)&wpk[(size_t)pr * NRES + kblock * 64 + kk];
      #pragma unroll
      for (int j = 0; j < 8; ++j) BT[kk + j][n] = v[j];
    }
    __syncthreads();
    const float* pa = &We1[(size_t)(hrow0 + l15) * NRES + n0 + l4 * 8];
    float4 a0 = *(const float4*)pa;
    float4 a1 = *(const float4*)(pa + 4);
    f16x8 af;
    af[0]=(_Float16)a0.x; af[1]=(_Float16)a0.y; af[2]=(_Float16)a0.z; af[3]=(_Float16)a0.w;
    af[4]=(_Float16)a1.x; af[5]=(_Float16)a1.y; af[6]=(_Float16)a1.z; af[7]=(_Float16)a1.w;
    #pragma unroll
    for (int kt = 0; kt < 4; ++kt) {
      f16x8 bf = *(const f16x8*)&BT[kt * 16 + l15][l4 * 8];
      acc[kt] = MFMA(af, bf, acc[kt]);
    }
    __syncthreads();
  }
  #pragma unroll
  for (int kt = 0; kt < 4; ++kt)
    #pragma unroll
    for (int i = 0; i < 4; ++i) {
      int h = hrow0 + l4 * 4 + i;
      int k = kblock * 64 + kt * 16 + l15;
      wh1[(size_t)h * NRES + k] = (_Float16)acc[kt][i];
    }
}

// ---------------- all-poll-all barrier, NO acquire (ring buffers make caches safe) ----------------
__device__ __forceinline__ void gbar4(unsigned* slots, int b, unsigned phase) {
  asm volatile("s_waitcnt vmcnt(0)" ::: "memory");   // sc1 stores acked at coherence point
  __syncthreads();
  if (threadIdx.x == 0)
    __hip_atomic_store(slots + (size_t)b * 16, phase, __ATOMIC_RELAXED, __HIP_MEMORY_SCOPE_AGENT);
  unsigned spins = 0;
  for (;;) {
    unsigned v = __hip_atomic_load(slots + (size_t)threadIdx.x * 16,
                                   __ATOMIC_RELAXED, __HIP_MEMORY_SCOPE_AGENT);
    if (__syncthreads_and((int)(v >= phase))) break;
    if (++spins > (1u << 18)) break;   // safety bail: wrong answer, not hang
    __builtin_amdgcn_s_sleep(2);
  }
  __syncthreads();
}

// ---------------- main persistent kernel ----------------

__global__ void __launch_bounds__(256, 2) k_main(
    const float* __restrict__ x,
    const float* __restrict__ ln_g, const float* __restrict__ ln_b,
    const float* __restrict__ be2v, const float* __restrict__ be3v,
    const float* __restrict__ w_mu, const float* __restrict__ w_rho,
    const float* __restrict__ b_mu, const float* __restrict__ b_rho,
    const float* __restrict__ w_eps, const float* __restrict__ b_eps,
    const _Float16* __restrict__ wpk, const _Float16* __restrict__ wh1,
    const float* __restrict__ bias_big,
    const _Float16* __restrict__ we2h, const _Float16* __restrict__ we3h,
    const _Float16* __restrict__ winh,
    _Float16* s16, _Float16* g2buf,
    unsigned* cnt, float* __restrict__ out)
{
  const int b = blockIdx.x, tid = threadIdx.x;
  unsigned* fg2   = cnt;          // 4 flags, one 64B line each (stride 16 u32)
  unsigned* slots = cnt + 64;     // 256 lines, stride 16 u32

  const int wv = tid >> 6, lane = tid & 63;
  const int l4 = lane >> 4, l15 = lane & 15;

  __shared__ float    lds_red[4][64][17];   // K-split reduce (S1 and h-duty)
  __shared__ _Float16 lds_w2[128][136];     // We2 resident
  __shared__ _Float16 lds_h1[16][136];      // h-duty: gelu(LN(h1)) then g2 bounce
  __shared__ _Float16 lds_x[64][40];        // x_t all 64 rows (f16)
  __shared__ _Float16 lds_ns[64][16];       // new-state bounce (8 cols + pad)

  const bool hduty = (b < 4);
  const int  hrt   = b;                     // h-duty row-tile (rows 16b..16b+15)

  // ---- S1 weights: packed [res8|att8] for cols 8b..8b+8, full K in VGPRs ----
  f16x8 Bf[16];
  #pragma unroll
  for (int ks = 0; ks < 16; ++ks)
    Bf[ks] = *(const f16x8*)&wpk[(size_t)(b * 16 + l15) * NRES + wv * 512 + ks * 32 + l4 * 8];

  // ---- update-phase constants (cols 8b + l15, valid for l15 < 8) ----
  const int mycol = 8 * b + (l15 & 7);
  const bool colv = (l15 < 8);
  f16x8 zf;
  #pragma unroll
  for (int j = 0; j < 8; ++j) zf[j] = (_Float16)0.f;
  f16x8 We3f[4];
  f16x8 Winf = zf;
  if (colv) {
    #pragma unroll
    for (int ks = 0; ks < 4; ++ks)
      We3f[ks] = *(const f16x8*)&we3h[(size_t)mycol * HDIM + ks * 32 + l4 * 8];
    Winf = *(const f16x8*)&winh[(size_t)mycol * DIN + l4 * 8];
  } else {
    #pragma unroll
    for (int ks = 0; ks < 4; ++ks) We3f[ks] = zf;
  }
  const float be3r  = colv ? be3v[mycol] : 0.f;
  const float battr = colv ? bias_big[2048 + mycol] : 0.f;

  // ---- h-duty constants ----
  float g8[8], bb8[8], bh8[8];
  #pragma unroll
  for (int ct = 0; ct < 8; ++ct) {
    g8[ct]  = ln_g[ct * 16 + l15];
    bb8[ct] = ln_b[ct * 16 + l15];
    bh8[ct] = bias_big[4096 + ct * 16 + l15];
  }
  float be2r[2];
  #pragma unroll
  for (int ct = 0; ct < 2; ++ct) be2r[ct] = be2v[(wv * 2 + ct) * 16 + l15];

  { // stage We2 into LDS once
    int row = tid >> 1, half = tid & 1;
    #pragma unroll
    for (int j = 0; j < 8; ++j)
      *(f16x8*)&lds_w2[row][half * 64 + j * 8] =
          *(const f16x8*)&we2h[(size_t)row * HDIM + half * 64 + j * 8];
  }
  __syncthreads();

  const f32x4 zero = {0.f, 0.f, 0.f, 0.f};
  const int laneR = (l4 << 4) | (l15 & 7);   // rrv source lane in lds_red
  const int laneA = laneR + 8;               // satt source lane

  for (int t = 0; t < TSTEPS; ++t) {
    // ring-buffered state & g2: addresses are never re-read before guaranteed L2 eviction
    const _Float16* sread = s16 + (size_t)(t & (RING - 1)) * S16N;
    _Float16* swrite      = s16 + (size_t)((t + 1) & (RING - 1)) * S16N;
    const _Float16* g2r   = g2buf + (size_t)(t & (RING - 1)) * G2N;
    _Float16* g2w         = g2buf + (size_t)(t & (RING - 1)) * G2N;

    // ========== h-duty FIRST: h1 -> LN -> GELU -> We2 -> GELU -> publish g2 ==========
    if (hduty) {
      f32x4 hacc[8];
      #pragma unroll
      for (int ct = 0; ct < 8; ++ct) hacc[ct] = zero;
      for (int kc = 0; kc < 16; ++kc) {
        f16x8 Ah = *(const f16x8*)&sread[(size_t)(hrt * 16 + l15) * NRES + wv * 512 + kc * 32 + l4 * 8];
        #pragma unroll
        for (int ct = 0; ct < 8; ++ct) {
          f16x8 Bh = *(const f16x8*)&wh1[(size_t)(ct * 16 + l15) * NRES + wv * 512 + kc * 32 + l4 * 8];
          hacc[ct] = MFMA(Ah, Bh, hacc[ct]);
        }
      }
      // 2-pass K-reduce across waves via lds_red
      float hv[32];
      #pragma unroll
      for (int ct = 0; ct < 4; ++ct)
        #pragma unroll
        for (int i = 0; i < 4; ++i) lds_red[wv][lane][ct * 4 + i] = hacc[ct][i];
      __syncthreads();
      #pragma unroll
      for (int ct = 0; ct < 4; ++ct)
        #pragma unroll
        for (int i = 0; i < 4; ++i)
          hv[ct * 4 + i] = lds_red[0][lane][ct * 4 + i] + lds_red[1][lane][ct * 4 + i]
                         + lds_red[2][lane][ct * 4 + i] + lds_red[3][lane][ct * 4 + i];
      __syncthreads();
      #pragma unroll
      for (int ct = 0; ct < 4; ++ct)
        #pragma unroll
        for (int i = 0; i < 4; ++i) lds_red[wv][lane][ct * 4 + i] = hacc[4 + ct][i];
      __syncthreads();
      #pragma unroll
      for (int ct = 4; ct < 8; ++ct)
        #pragma unroll
        for (int i = 0; i < 4; ++i)
          hv[ct * 4 + i] = lds_red[0][lane][(ct - 4) * 4 + i] + lds_red[1][lane][(ct - 4) * 4 + i]
                         + lds_red[2][lane][(ct - 4) * 4 + i] + lds_red[3][lane][(ct - 4) * 4 + i];
      __syncthreads();
      // bias + LayerNorm per row (rows l4*4+i; 128 cols = 8 ct x 16 l15)
      float s1v[4] = {0.f, 0.f, 0.f, 0.f}, s2v[4] = {0.f, 0.f, 0.f, 0.f};
      #pragma unroll
      for (int ct = 0; ct < 8; ++ct)
        #pragma unroll
        for (int i = 0; i < 4; ++i) {
          float v = hv[ct * 4 + i] + bh8[ct];
          hv[ct * 4 + i] = v; s1v[i] += v; s2v[i] += v * v;
        }
      #pragma unroll
      for (int m = 1; m < 16; m <<= 1)
        #pragma unroll
        for (int i = 0; i < 4; ++i) { s1v[i] += __shfl_xor(s1v[i], m); s2v[i] += __shfl_xor(s2v[i], m); }
      #pragma unroll
      for (int i = 0; i < 4; ++i) {
        float mu = s1v[i] * (1.f / 128.f);
        float var = s2v[i] * (1.f / 128.f) - mu * mu;
        float rs = rsqrtf(var + 1e-5f);
        if (wv == 0) {
          #pragma unroll
          for (int ct = 0; ct < 8; ++ct) {
            float hn = (hv[ct * 4 + i] - mu) * rs * g8[ct] + bb8[ct];
            lds_h1[l4 * 4 + i][ct * 16 + l15] = (_Float16)gelu_exact(hn);
          }
        }
      }
      __syncthreads();
      // h2 = gelu(h1g @ We2^T + be2): wave wv does col-tiles wv*2, wv*2+1
      f32x4 c0 = zero, c1 = zero;
      #pragma unroll
      for (int ks = 0; ks < 4; ++ks) {
        f16x8 af = *(const f16x8*)&lds_h1[l15][ks * 32 + l4 * 8];
        f16x8 b0 = *(const f16x8*)&lds_w2[(wv * 2 + 0) * 16 + l15][ks * 32 + l4 * 8];
        f16x8 b1 = *(const f16x8*)&lds_w2[(wv * 2 + 1) * 16 + l15][ks * 32 + l4 * 8];
        c0 = MFMA(af, b0, c0);
        c1 = MFMA(af, b1, c1);
      }
      __syncthreads();   // MFMA reads of lds_h1 done; reuse as g2 bounce
      #pragma unroll
      for (int i = 0; i < 4; ++i) {
        int rr = l4 * 4 + i;
        lds_h1[rr][(wv * 2 + 0) * 16 + l15] = (_Float16)gelu_exact(c0[i] + be2r[0]);
        lds_h1[rr][(wv * 2 + 1) * 16 + l15] = (_Float16)gelu_exact(c1[i] + be2r[1]);
      }
      __syncthreads();
      { // publish g2 tile (16 rows x 128) to the ring slot with 16B write-through stores
        int row = tid >> 4, ch = tid & 15;
        f16x8 v = *(const f16x8*)&lds_h1[row][ch * 8];
        stg16(&g2w[(size_t)(hrt * 16 + row) * HDIM + ch * 8], __builtin_bit_cast(f32x4, v));
      }
      asm volatile("s_waitcnt vmcnt(0)" ::: "memory");
      __syncthreads();
      if (tid == 0)
        __hip_atomic_store(fg2 + (size_t)hrt * 16, (unsigned)(t + 1),
                           __ATOMIC_RELAXED, __HIP_MEMORY_SCOPE_AGENT);
    }

    // ========== S1 main (uniform, all blocks): [rrv|satt] partials in LDS ==========
    f32x4 a0 = zero, a1 = zero, a2 = zero, a3 = zero;
    #pragma unroll
    for (int ks = 0; ks < 16; ++ks) {
      const int kk = wv * 512 + ks * 32 + l4 * 8;
      f16x8 A0 = *(const f16x8*)&sread[(size_t)(l15) * NRES + kk];
      f16x8 A1 = *(const f16x8*)&sread[(size_t)(16 + l15) * NRES + kk];
      f16x8 A2 = *(const f16x8*)&sread[(size_t)(32 + l15) * NRES + kk];
      f16x8 A3 = *(const f16x8*)&sread[(size_t)(48 + l15) * NRES + kk];
      a0 = MFMA(A0, Bf[ks], a0);
      a1 = MFMA(A1, Bf[ks], a1);
      a2 = MFMA(A2, Bf[ks], a2);
      a3 = MFMA(A3, Bf[ks], a3);
    }
    __syncthreads();   // h-duty lds_red traffic fully done before overwrite
    #pragma unroll
    for (int i = 0; i < 4; ++i) {
      lds_red[wv][lane][0 + i]  = a0[i];
      lds_red[wv][lane][4 + i]  = a1[i];
      lds_red[wv][lane][8 + i]  = a2[i];
      lds_red[wv][lane][12 + i] = a3[i];
    }
    { // stage x_t: all 64 rows x 32 (f16)
      int row = tid >> 2, k0 = (tid & 3) * 8;
      const float* xs = &x[((size_t)row * TSTEPS + t) * DIN + k0];
      float4 v0 = *(const float4*)xs;
      float4 v1 = *(const float4*)(xs + 4);
      _Float16* d = &lds_x[row][k0];
      d[0]=(_Float16)v0.x; d[1]=(_Float16)v0.y; d[2]=(_Float16)v0.z; d[3]=(_Float16)v0.w;
      d[4]=(_Float16)v1.x; d[5]=(_Float16)v1.y; d[6]=(_Float16)v1.z; d[7]=(_Float16)v1.w;
    }
    // ========== wait for g2 flags (all-threads, overlapped with S1 above; no acquire) ==========
    {
      unsigned spins = 0;
      for (;;) {
        bool ok = true;
        if (tid < 4) {
          unsigned v = __hip_atomic_load(fg2 + (size_t)tid * 16,
                                         __ATOMIC_RELAXED, __HIP_MEMORY_SCOPE_AGENT);
          ok = (v >= (unsigned)(t + 1));
        }
        if (__syncthreads_and((int)ok)) break;
        if (++spins > (1u << 18)) break;
        __builtin_amdgcn_s_sleep(2);
      }
      __syncthreads();
    }

    // ========== update: phys + input + [rrv|satt] -> new state (wave wv: rows wv*16..+15) ==========
    {
      f32x4 accp = zero;
      #pragma unroll
      for (int kc = 0; kc < 4; ++kc) {
        f16x8 ag = *(const f16x8*)&g2r[(size_t)(wv * 16 + l15) * HDIM + kc * 32 + l4 * 8];
        accp = MFMA(ag, We3f[kc], accp);
      }
      f16x8 ax = *(const f16x8*)&lds_x[wv * 16 + l15][l4 * 8];
      f32x4 acci = MFMA(ax, Winf, zero);
      #pragma unroll
      for (int i = 0; i < 4; ++i) {
        float rr = lds_red[0][laneR][wv * 4 + i] + lds_red[1][laneR][wv * 4 + i]
                 + lds_red[2][laneR][wv * 4 + i] + lds_red[3][laneR][wv * 4 + i];
        float sa = lds_red[0][laneA][wv * 4 + i] + lds_red[1][laneA][wv * 4 + i]
                 + lds_red[2][laneA][wv * 4 + i] + lds_red[3][laneA][wv * 4 + i];
        float ns = 0.7f * (sa + battr) + 0.3f * tanhf(acci[i] + rr + accp[i] + be3r);
        if (colv) lds_ns[wv * 16 + l4 * 4 + i][l15] = (_Float16)ns;
      }
    }
    __syncthreads();
    if (tid < 64) {  // coalesced state store to the ring write slot: 64 rows x 16B
      f16x8 v = *(const f16x8*)&lds_ns[tid][0];
      stg16(&swrite[(size_t)tid * NRES + 8 * b], __builtin_bit_cast(f32x4, v));
    }

    // ========== single global barrier per step (all-poll-all, no acquire) ==========
    gbar4(slots, b, (unsigned)(t + 1));
  }

  // ---- Bayesian output head (blocks 0..63, post final barrier) ----
  // final state written at t=255 -> ring slot (255+1)&63 = 0 -> s16 base (cold addresses)
  if (b < BBATCH) {
    float* red = &lds_red[0][0][0];
    int o = tid >> 4, sg = tid & 15;
    float p = 0.f;
    for (int n = sg * 128; n < sg * 128 + 128; ++n) {
      float sv = (float)s16[(size_t)b * NRES + n];
      float w = w_mu[(size_t)o * NRES + n]
              + log1pf(expf(w_rho[(size_t)o * NRES + n])) * w_eps[(size_t)o * NRES + n];
      p += sv * w;
    }
    red[o * 17 + sg] = p;
    __syncthreads();
    if (tid < DOUT) {
      float sum = 0.f;
      for (int q = 0; q < 16; ++q) sum += red[tid * 17 + q];
      float bs = b_mu[tid] + log1pf(expf(b_rho[tid])) * b_eps[tid];
      out[b * DOUT + tid] = sum + bs;
    }
  }
}

// ---------------- host ----------------

extern "C" void kernel_launch(void* const* d_in, const int* in_sizes, int n_in,
                              void* d_out, int out_size, void* d_ws, size_t ws_size,
                              hipStream_t stream) {
  (void)in_sizes; (void)n_in; (void)out_size; (void)ws_size;
  const float* x     = (const float*)d_in[0];
  const float* W_in  = (const float*)d_in[1];
  const float* W_res = (const float*)d_in[2];
  const float* Wv    = (const float*)d_in[3];
  const float* bv    = (const float*)d_in[4];
  const float* Wproj = (const float*)d_in[5];
  const float* bproj = (const float*)d_in[6];
  const float* We1   = (const float*)d_in[7];
  const float* be1   = (const float*)d_in[8];
  const float* ln_g  = (const float*)d_in[9];
  const float* ln_b  = (const float*)d_in[10];
  const float* We2   = (const float*)d_in[11];
  const float* be2   = (const float*)d_in[12];
  const float* We3   = (const float*)d_in[13];
  const float* be3   = (const float*)d_in[14];
  const float* w_mu  = (const float*)d_in[15];
  const float* w_rho = (const float*)d_in[16];
  const float* b_mu  = (const float*)d_in[17];
  const float* b_rho = (const float*)d_in[18];
  const float* w_eps = (const float*)d_in[19];
  const float* b_eps = (const float*)d_in[20];
  float* out = (float*)d_out;

  char* ws = (char*)d_ws;
  _Float16* wpk      = (_Float16*)(ws + OFF_WPK);
  _Float16* wh1      = (_Float16*)(ws + OFF_WH1);
  float*    bias_big = (float*)(ws + OFF_BIAS);
  _Float16* we2h     = (_Float16*)(ws + OFF_WE2H);
  _Float16* we3h     = (_Float16*)(ws + OFF_WE3H);
  _Float16* winh     = (_Float16*)(ws + OFF_WINH);
  _Float16* g2buf    = (_Float16*)(ws + OFF_G2);
  unsigned* cnt      = (unsigned*)(ws + OFF_CNT);
  _Float16* s16      = (_Float16*)(ws + OFF_S16);

  hipMemsetAsync(bias_big, 0, 4224 * sizeof(float), stream);
  hipMemsetAsync(s16, 0, (size_t)S16N * sizeof(_Float16), stream);  // ring slot 0 only
  hipMemsetAsync(cnt, 0, (64 + 4096) * 4, stream);   // fg2 lines + slot lines

  k_castres<<<2048, 256, 0, stream>>>(W_res, wpk);                 // res -> packed rows
  k_cast<<<64,   256, 0, stream>>>(We2, we2h, HDIM * HDIM);
  k_cast<<<1024, 256, 0, stream>>>(We3, we3h, NRES * HDIM);
  k_cast<<<256,  256, 0, stream>>>(W_in, winh, NRES * DIN);
  k_batt<<<NRES, 256, 0, stream>>>(Wproj, bv, bproj, bias_big);
  k_gemm1<<<dim3(32, 32), 256, 0, stream>>>(Wproj, Wv, wpk);       // att -> packed rows
  k_bh1<<<HDIM, 256, 0, stream>>>(We1, be1, bias_big);
  k_gemm2<<<dim3(32, 2), 256, 0, stream>>>(We1, wpk, wh1);         // wh1[128][2048]

  k_main<<<NBLK, 256, 0, stream>>>(x, ln_g, ln_b, be2, be3,
                                   w_mu, w_rho, b_mu, b_rho, w_eps, b_eps,
                                   wpk, wh1, bias_big, we2h, we3h, winh,
                                   s16, g2buf, cnt, out);
}

// Round 12
// 8796.107 us; speedup vs baseline: 1.1195x; 1.0371x over previous
//
#include <hip/hip_runtime.h>
#include <hip/hip_fp16.h>
#include <cstdint>
#include <cstddef>

typedef _Float16 f16x8 __attribute__((ext_vector_type(8)));
typedef float    f32x4 __attribute__((ext_vector_type(4)));

#define MFMA(A,B,C) __builtin_amdgcn_mfma_f32_16x16x32_f16((A),(B),(C),0,0,0)

// ---- problem constants ----
#define NRES  2048
#define DIN   32
#define DOUT  16
#define HDIM  128
#define BBATCH 64
#define TSTEPS 256
#define NBLK  256      // 1 block/CU. Blocks 0-3: h-duty only. Blocks 4-255: S1 strip b.
                       // Blocks 4-7 additionally carry strip b-4 (cols 0..31).
#define S16N  (BBATCH * NRES)
#define RING  64
#define G2N   (BBATCH * HDIM)

// ---- workspace layout (bytes) ----
#define OFF_WPK   ((size_t)0)          // packed [res8|att8] weights: 4096*2048 f16 = 16,777,216
#define OFF_WH1   ((size_t)16777216)   // 128*2048 f16 -> 17,301,504
#define OFF_BIAS  ((size_t)17301504)   // 4224 f32     -> 17,318,400
#define OFF_WE2H  ((size_t)17318400)   // 128*128 f16  -> 17,351,168
#define OFF_WE3H  ((size_t)17351168)   // 2048*128 f16 -> 17,875,456
#define OFF_WINH  ((size_t)17875456)   // 2048*32 f16  -> 18,006,528
#define OFF_G2    ((size_t)18006528)   // RING x 64*128 f16 -> 19,055,104
#define OFF_CNT   ((size_t)19055104)   // fg2: 4 lines + slots: 256 lines
#define OFF_S16   ((size_t)19072000)   // RING x 64*2048 f16 -> 35,849,216

__device__ __forceinline__ float gelu_exact(float v) {
  return 0.5f * v * (1.0f + erff(v * 0.70710678118654752f));
}

__device__ __forceinline__ void stg16(void* p, f32x4 v) {
  asm volatile("global_store_dwordx4 %0, %1, off sc0 sc1" :: "v"(p), "v"(v) : "memory");
}

// ---------------- prep kernels (verified R8-R11) ----------------

__global__ void k_cast(const float* __restrict__ src, _Float16* __restrict__ dst, int n) {
  int i = blockIdx.x * blockDim.x + threadIdx.x;
  int stride = gridDim.x * blockDim.x;
  for (; i < n; i += stride) dst[i] = (_Float16)src[i];
}

__global__ void k_castres(const float* __restrict__ W_res, _Float16* __restrict__ wpk) {
  int c = blockIdx.x, k0 = threadIdx.x * 8;
  int pr = (c >> 3) * 16 + (c & 7);
  const float* s = &W_res[(size_t)c * NRES + k0];
  _Float16* d = &wpk[(size_t)pr * NRES + k0];
  #pragma unroll
  for (int j = 0; j < 8; ++j) d[j] = (_Float16)s[j];
}

__global__ void k_batt(const float* __restrict__ Wproj, const float* __restrict__ bv,
                       const float* __restrict__ bproj, float* __restrict__ bias_big) {
  int c = blockIdx.x, tid = threadIdx.x;
  float p = 0.f;
  for (int k = tid; k < NRES; k += 256) p += Wproj[(size_t)c * NRES + k] * bv[k];
  for (int m = 1; m < 64; m <<= 1) p += __shfl_xor(p, m);
  __shared__ float r4[4];
  if ((tid & 63) == 0) r4[tid >> 6] = p;
  __syncthreads();
  if (tid == 0) bias_big[2048 + c] = r4[0] + r4[1] + r4[2] + r4[3] + bproj[c];
}

__global__ void k_bh1(const float* __restrict__ We1, const float* __restrict__ be1,
                      float* __restrict__ bias_big) {
  int h = blockIdx.x, tid = threadIdx.x;
  float p = 0.f;
  for (int n = tid; n < NRES; n += 256) p += We1[(size_t)h * NRES + n] * bias_big[2048 + n];
  for (int m = 1; m < 64; m <<= 1) p += __shfl_xor(p, m);
  __shared__ float r4[4];
  if ((tid & 63) == 0) r4[tid >> 6] = p;
  __syncthreads();
  if (tid == 0) bias_big[4096 + h] = r4[0] + r4[1] + r4[2] + r4[3] + be1[h];
}

__global__ void __launch_bounds__(256) k_gemm1(const float* __restrict__ Wproj,
                                               const float* __restrict__ Wv,
                                               _Float16* __restrict__ wpk) {
  __shared__ _Float16 BT[64][40];
  const int kblock = blockIdx.x, cblock = blockIdx.y;
  const int tid = threadIdx.x, wv = tid >> 6, lane = tid & 63;
  const int l4 = lane >> 4, l15 = lane & 15;
  const int crow0 = cblock * 64 + wv * 16;
  f32x4 acc[4];
  f32x4 zero = {0.f, 0.f, 0.f, 0.f};
  for (int i = 0; i < 4; ++i) acc[i] = zero;

  for (int mc = 0; mc < 64; ++mc) {
    const int m0 = mc * 32;
    {
      int m = tid >> 3, kk = (tid & 7) * 8;
      const float* src = &Wv[(size_t)(m0 + m) * NRES + kblock * 64 + kk];
      float4 v0 = *(const float4*)src;
      float4 v1 = *(const float4*)(src + 4);
      float tmp[8] = {v0.x, v0.y, v0.z, v0.w, v1.x, v1.y, v1.z, v1.w};
      #pragma unroll
      for (int j = 0; j < 8; ++j) BT[kk + j][m] = (_Float16)tmp[j];
    }
    __syncthreads();
    const float* pa = &Wproj[(size_t)(crow0 + l15) * NRES + m0 + l4 * 8];
    float4 a0 = *(const float4*)pa;
    float4 a1 = *(const float4*)(pa + 4);
    f16x8 af;
    af[0]=(_Float16)a0.x; af[1]=(_Float16)a0.y; af[2]=(_Float16)a0.z; af[3]=(_Float16)a0.w;
    af[4]=(_Float16)a1.x; af[5]=(_Float16)a1.y; af[6]=(_Float16)a1.z; af[7]=(_Float16)a1.w;
    #pragma unroll
    for (int kt = 0; kt < 4; ++kt) {
      f16x8 bf = *(const f16x8*)&BT[kt * 16 + l15][l4 * 8];
      acc[kt] = MFMA(af, bf, acc[kt]);
    }
    __syncthreads();
  }
  #pragma unroll
  for (int kt = 0; kt < 4; ++kt)
    #pragma unroll
    for (int i = 0; i < 4; ++i) {
      int c = crow0 + l4 * 4 + i;
      int k = kblock * 64 + kt * 16 + l15;
      int pr = (c >> 3) * 16 + 8 + (c & 7);
      wpk[(size_t)pr * NRES + k] = (_Float16)acc[kt][i];
    }
}

__global__ void __launch_bounds__(256) k_gemm2(const float* __restrict__ We1,
                                               const _Float16* __restrict__ wpk,
                                               _Float16* __restrict__ wh1) {
  __shared__ _Float16 BT[64][40];
  const int kblock = blockIdx.x, hblock = blockIdx.y;
  const int tid = threadIdx.x, wv = tid >> 6, lane = tid & 63;
  const int l4 = lane >> 4, l15 = lane & 15;
  const int hrow0 = hblock * 64 + wv * 16;
  f32x4 acc[4];
  f32x4 zero = {0.f, 0.f, 0.f, 0.f};
  for (int i = 0; i < 4; ++i) acc[i] = zero;

  for (int nc = 0; nc < 64; ++nc) {
    const int n0 = nc * 32;
    {
      int n = tid >> 3, kk = (tid & 7) * 8;
      int nn = n0 + n;
      int pr = (nn >> 3) * 16 + 8 + (nn & 7);
      f16x8 v = *(const f16x8*)&wpk[(size_t)pr * NRES + kblock * 64 + kk];
      #pragma unroll
      for (int j = 0; j < 8; ++j) BT[kk + j][n] = v[j];
    }
    __syncthreads();
    const float* pa = &We1[(size_t)(hrow0 + l15) * NRES + n0 + l4 * 8];
    float4 a0 = *(const float4*)pa;
    float4 a1 = *(const float4*)(pa + 4);
    f16x8 af;
    af[0]=(_Float16)a0.x; af[1]=(_Float16)a0.y; af[2]=(_Float16)a0.z; af[3]=(_Float16)a0.w;
    af[4]=(_Float16)a1.x; af[5]=(_Float16)a1.y; af[6]=(_Float16)a1.z; af[7]=(_Float16)a1.w;
    #pragma unroll
    for (int kt = 0; kt < 4; ++kt) {
      f16x8 bf = *(const f16x8*)&BT[kt * 16 + l15][l4 * 8];
      acc[kt] = MFMA(af, bf, acc[kt]);
    }
    __syncthreads();
  }
  #pragma unroll
  for (int kt = 0; kt < 4; ++kt)
    #pragma unroll
    for (int i = 0; i < 4; ++i) {
      int h = hrow0 + l4 * 4 + i;
      int k = kblock * 64 + kt * 16 + l15;
      wh1[(size_t)h * NRES + k] = (_Float16)acc[kt][i];
    }
}

// ---------------- barrier: independent spin (no intra-loop block barrier) ----------------
__device__ __forceinline__ void gbar5(unsigned* slots, int b, unsigned phase) {
  asm volatile("s_waitcnt vmcnt(0)" ::: "memory");   // sc1 stores acked at coherence point
  __syncthreads();
  if (threadIdx.x == 0)
    __hip_atomic_store(slots + (size_t)b * 16, phase, __ATOMIC_RELAXED, __HIP_MEMORY_SCOPE_AGENT);
  unsigned spins = 0;
  while (__hip_atomic_load(slots + (size_t)threadIdx.x * 16,
                           __ATOMIC_RELAXED, __HIP_MEMORY_SCOPE_AGENT) < phase) {
    __builtin_amdgcn_s_sleep(1);
    if (++spins > (1u << 18)) break;   // safety bail: wrong answer, not hang
  }
  __syncthreads();
}

// ---------------- main persistent kernel ----------------

__global__ void __launch_bounds__(256) k_main(
    const float* __restrict__ x,
    const float* __restrict__ ln_g, const float* __restrict__ ln_b,
    const float* __restrict__ be2v, const float* __restrict__ be3v,
    const float* __restrict__ w_mu, const float* __restrict__ w_rho,
    const float* __restrict__ b_mu, const float* __restrict__ b_rho,
    const float* __restrict__ w_eps, const float* __restrict__ b_eps,
    const _Float16* __restrict__ wpk, const _Float16* __restrict__ wh1,
    const float* __restrict__ bias_big,
    const _Float16* __restrict__ we2h, const _Float16* __restrict__ we3h,
    const _Float16* __restrict__ winh,
    _Float16* s16, _Float16* g2buf,
    unsigned* cnt, float* __restrict__ out)
{
  const int b = blockIdx.x, tid = threadIdx.x;
  unsigned* fg2   = cnt;          // 4 flags, one 64B line each
  unsigned* slots = cnt + 64;     // 256 lines

  const int wv = tid >> 6, lane = tid & 63;
  const int l4 = lane >> 4, l15 = lane & 15;

  __shared__ float    lds_red[4][64][17];   // K-split reduce
  __shared__ _Float16 lds_w2[128][136];     // We2 resident (h-blocks)
  __shared__ _Float16 lds_h1[16][136];      // h-duty scratch
  __shared__ _Float16 lds_x[64][40];        // x_t (workers)
  __shared__ _Float16 lds_ns[64][24];       // new-state bounce: cols 0-7 = strip A, 8-15 = strip B

  const bool hduty = (b < 4);
  const bool dual  = (b >= 4 && b < 8);
  const int  hrt   = b;

  // ---- S1 weights: strip A = b (blocks >= 4); strip B = b-4 (blocks 4-7, streamed) ----
  f16x8 Bf[16];
  if (!hduty) {
    #pragma unroll
    for (int ks = 0; ks < 16; ++ks)
      Bf[ks] = *(const f16x8*)&wpk[(size_t)(b * 16 + l15) * NRES + wv * 512 + ks * 32 + l4 * 8];
  }
  const _Float16* wpkB = &wpk[(size_t)((dual ? (b - 4) : 0) * 16 + l15) * NRES + wv * 512 + l4 * 8];

  // ---- update-phase constants: per-lane column ----
  // lanes l15<8 -> strip A col; lanes 8..15 -> strip B col (dual blocks only)
  int mycol = -1;
  if (!hduty) {
    if (l15 < 8) mycol = 8 * b + l15;
    else if (dual) mycol = 8 * (b - 4) + (l15 - 8);
  }
  const bool colvx = (mycol >= 0);
  f16x8 zf;
  #pragma unroll
  for (int j = 0; j < 8; ++j) zf[j] = (_Float16)0.f;
  f16x8 We3f[4];
  f16x8 Winf = zf;
  if (colvx) {
    #pragma unroll
    for (int ks = 0; ks < 4; ++ks)
      We3f[ks] = *(const f16x8*)&we3h[(size_t)mycol * HDIM + ks * 32 + l4 * 8];
    Winf = *(const f16x8*)&winh[(size_t)mycol * DIN + l4 * 8];
  } else {
    #pragma unroll
    for (int ks = 0; ks < 4; ++ks) We3f[ks] = zf;
  }
  const float be3r  = colvx ? be3v[mycol] : 0.f;
  const float battr = colvx ? bias_big[2048 + mycol] : 0.f;

  // ---- h-duty constants ----
  float g8[8], bb8[8], bh8[8];
  #pragma unroll
  for (int ct = 0; ct < 8; ++ct) {
    g8[ct]  = ln_g[ct * 16 + l15];
    bb8[ct] = ln_b[ct * 16 + l15];
    bh8[ct] = bias_big[4096 + ct * 16 + l15];
  }
  float be2r[2];
  #pragma unroll
  for (int ct = 0; ct < 2; ++ct) be2r[ct] = be2v[(wv * 2 + ct) * 16 + l15];

  { // stage We2 into LDS once (used by h-blocks)
    int row = tid >> 1, half = tid & 1;
    #pragma unroll
    for (int j = 0; j < 8; ++j)
      *(f16x8*)&lds_w2[row][half * 64 + j * 8] =
          *(const f16x8*)&we2h[(size_t)row * HDIM + half * 64 + j * 8];
  }
  __syncthreads();

  const f32x4 zero = {0.f, 0.f, 0.f, 0.f};
  const int laneR = (l4 << 4) | (l15 & 7);
  const int laneA = laneR + 8;

  for (int t = 0; t < TSTEPS; ++t) {
    const _Float16* sread = s16 + (size_t)(t & (RING - 1)) * S16N;
    _Float16* swrite      = s16 + (size_t)((t + 1) & (RING - 1)) * S16N;
    const _Float16* g2r   = g2buf + (size_t)(t & (RING - 1)) * G2N;
    _Float16* g2w         = g2buf + (size_t)(t & (RING - 1)) * G2N;

    if (hduty) {
      // ========== h-block: h1 -> LN -> GELU -> We2 -> GELU -> publish g2 + flag ==========
      f32x4 hacc[8];
      #pragma unroll
      for (int ct = 0; ct < 8; ++ct) hacc[ct] = zero;
      for (int kc = 0; kc < 16; ++kc) {
        f16x8 Ah = *(const f16x8*)&sread[(size_t)(hrt * 16 + l15) * NRES + wv * 512 + kc * 32 + l4 * 8];
        #pragma unroll
        for (int ct = 0; ct < 8; ++ct) {
          f16x8 Bh = *(const f16x8*)&wh1[(size_t)(ct * 16 + l15) * NRES + wv * 512 + kc * 32 + l4 * 8];
          hacc[ct] = MFMA(Ah, Bh, hacc[ct]);
        }
      }
      float hv[32];
      #pragma unroll
      for (int ct = 0; ct < 4; ++ct)
        #pragma unroll
        for (int i = 0; i < 4; ++i) lds_red[wv][lane][ct * 4 + i] = hacc[ct][i];
      __syncthreads();
      #pragma unroll
      for (int ct = 0; ct < 4; ++ct)
        #pragma unroll
        for (int i = 0; i < 4; ++i)
          hv[ct * 4 + i] = lds_red[0][lane][ct * 4 + i] + lds_red[1][lane][ct * 4 + i]
                         + lds_red[2][lane][ct * 4 + i] + lds_red[3][lane][ct * 4 + i];
      __syncthreads();
      #pragma unroll
      for (int ct = 0; ct < 4; ++ct)
        #pragma unroll
        for (int i = 0; i < 4; ++i) lds_red[wv][lane][ct * 4 + i] = hacc[4 + ct][i];
      __syncthreads();
      #pragma unroll
      for (int ct = 4; ct < 8; ++ct)
        #pragma unroll
        for (int i = 0; i < 4; ++i)
          hv[ct * 4 + i] = lds_red[0][lane][(ct - 4) * 4 + i] + lds_red[1][lane][(ct - 4) * 4 + i]
                         + lds_red[2][lane][(ct - 4) * 4 + i] + lds_red[3][lane][(ct - 4) * 4 + i];
      __syncthreads();
      float s1v[4] = {0.f, 0.f, 0.f, 0.f}, s2v[4] = {0.f, 0.f, 0.f, 0.f};
      #pragma unroll
      for (int ct = 0; ct < 8; ++ct)
        #pragma unroll
        for (int i = 0; i < 4; ++i) {
          float v = hv[ct * 4 + i] + bh8[ct];
          hv[ct * 4 + i] = v; s1v[i] += v; s2v[i] += v * v;
        }
      #pragma unroll
      for (int m = 1; m < 16; m <<= 1)
        #pragma unroll
        for (int i = 0; i < 4; ++i) { s1v[i] += __shfl_xor(s1v[i], m); s2v[i] += __shfl_xor(s2v[i], m); }
      #pragma unroll
      for (int i = 0; i < 4; ++i) {
        float mu = s1v[i] * (1.f / 128.f);
        float var = s2v[i] * (1.f / 128.f) - mu * mu;
        float rs = rsqrtf(var + 1e-5f);
        if (wv == 0) {
          #pragma unroll
          for (int ct = 0; ct < 8; ++ct) {
            float hn = (hv[ct * 4 + i] - mu) * rs * g8[ct] + bb8[ct];
            lds_h1[l4 * 4 + i][ct * 16 + l15] = (_Float16)gelu_exact(hn);
          }
        }
      }
      __syncthreads();
      f32x4 c0 = zero, c1 = zero;
      #pragma unroll
      for (int ks = 0; ks < 4; ++ks) {
        f16x8 af = *(const f16x8*)&lds_h1[l15][ks * 32 + l4 * 8];
        f16x8 b0 = *(const f16x8*)&lds_w2[(wv * 2 + 0) * 16 + l15][ks * 32 + l4 * 8];
        f16x8 b1 = *(const f16x8*)&lds_w2[(wv * 2 + 1) * 16 + l15][ks * 32 + l4 * 8];
        c0 = MFMA(af, b0, c0);
        c1 = MFMA(af, b1, c1);
      }
      __syncthreads();
      #pragma unroll
      for (int i = 0; i < 4; ++i) {
        int rr = l4 * 4 + i;
        lds_h1[rr][(wv * 2 + 0) * 16 + l15] = (_Float16)gelu_exact(c0[i] + be2r[0]);
        lds_h1[rr][(wv * 2 + 1) * 16 + l15] = (_Float16)gelu_exact(c1[i] + be2r[1]);
      }
      __syncthreads();
      {
        int row = tid >> 4, ch = tid & 15;
        f16x8 v = *(const f16x8*)&lds_h1[row][ch * 8];
        stg16(&g2w[(size_t)(hrt * 16 + row) * HDIM + ch * 8], __builtin_bit_cast(f32x4, v));
      }
      asm volatile("s_waitcnt vmcnt(0)" ::: "memory");
      __syncthreads();
      if (tid == 0)
        __hip_atomic_store(fg2 + (size_t)hrt * 16, (unsigned)(t + 1),
                           __ATOMIC_RELAXED, __HIP_MEMORY_SCOPE_AGENT);
    } else {
      // ========== worker: x-stage, S1 (A [+B]), reduce, flag wait, update, store ==========
      { // stage x_t: 64 rows x 32 (f16)
        int row = tid >> 2, k0 = (tid & 3) * 8;
        const float* xs = &x[((size_t)row * TSTEPS + t) * DIN + k0];
        float4 v0 = *(const float4*)xs;
        float4 v1 = *(const float4*)(xs + 4);
        _Float16* d = &lds_x[row][k0];
        d[0]=(_Float16)v0.x; d[1]=(_Float16)v0.y; d[2]=(_Float16)v0.z; d[3]=(_Float16)v0.w;
        d[4]=(_Float16)v1.x; d[5]=(_Float16)v1.y; d[6]=(_Float16)v1.z; d[7]=(_Float16)v1.w;
      }
      f32x4 a0 = zero, a1 = zero, a2 = zero, a3 = zero;
      f32x4 e0 = zero, e1 = zero, e2 = zero, e3 = zero;
      #pragma unroll
      for (int ks = 0; ks < 16; ++ks) {
        const int kk = wv * 512 + ks * 32 + l4 * 8;
        f16x8 A0 = *(const f16x8*)&sread[(size_t)(l15) * NRES + kk];
        f16x8 A1 = *(const f16x8*)&sread[(size_t)(16 + l15) * NRES + kk];
        f16x8 A2 = *(const f16x8*)&sread[(size_t)(32 + l15) * NRES + kk];
        f16x8 A3 = *(const f16x8*)&sread[(size_t)(48 + l15) * NRES + kk];
        a0 = MFMA(A0, Bf[ks], a0);
        a1 = MFMA(A1, Bf[ks], a1);
        a2 = MFMA(A2, Bf[ks], a2);
        a3 = MFMA(A3, Bf[ks], a3);
        if (dual) {
          f16x8 Bx = *(const f16x8*)&wpkB[ks * 32];
          e0 = MFMA(A0, Bx, e0);
          e1 = MFMA(A1, Bx, e1);
          e2 = MFMA(A2, Bx, e2);
          e3 = MFMA(A3, Bx, e3);
        }
      }
      __syncthreads();
      #pragma unroll
      for (int i = 0; i < 4; ++i) {
        lds_red[wv][lane][0 + i]  = a0[i];
        lds_red[wv][lane][4 + i]  = a1[i];
        lds_red[wv][lane][8 + i]  = a2[i];
        lds_red[wv][lane][12 + i] = a3[i];
      }
      __syncthreads();
      float rrA[4], saA[4], rrB[4], saB[4];
      #pragma unroll
      for (int i = 0; i < 4; ++i) {
        rrA[i] = lds_red[0][laneR][wv * 4 + i] + lds_red[1][laneR][wv * 4 + i]
               + lds_red[2][laneR][wv * 4 + i] + lds_red[3][laneR][wv * 4 + i];
        saA[i] = lds_red[0][laneA][wv * 4 + i] + lds_red[1][laneA][wv * 4 + i]
               + lds_red[2][laneA][wv * 4 + i] + lds_red[3][laneA][wv * 4 + i];
        rrB[i] = 0.f; saB[i] = 0.f;
      }
      if (dual) {
        __syncthreads();
        #pragma unroll
        for (int i = 0; i < 4; ++i) {
          lds_red[wv][lane][0 + i]  = e0[i];
          lds_red[wv][lane][4 + i]  = e1[i];
          lds_red[wv][lane][8 + i]  = e2[i];
          lds_red[wv][lane][12 + i] = e3[i];
        }
        __syncthreads();
        #pragma unroll
        for (int i = 0; i < 4; ++i) {
          rrB[i] = lds_red[0][laneR][wv * 4 + i] + lds_red[1][laneR][wv * 4 + i]
                 + lds_red[2][laneR][wv * 4 + i] + lds_red[3][laneR][wv * 4 + i];
          saB[i] = lds_red[0][laneA][wv * 4 + i] + lds_red[1][laneA][wv * 4 + i]
                 + lds_red[2][laneA][wv * 4 + i] + lds_red[3][laneA][wv * 4 + i];
        }
      }
      // ---- wait for g2 flags: independent spin, one exit sync ----
      if (tid < 4) {
        unsigned spins = 0;
        while (__hip_atomic_load(fg2 + (size_t)tid * 16,
                                 __ATOMIC_RELAXED, __HIP_MEMORY_SCOPE_AGENT) < (unsigned)(t + 1)) {
          __builtin_amdgcn_s_sleep(1);
          if (++spins > (1u << 18)) break;
        }
      }
      __syncthreads();
      // ---- update: phys + input + [rrv|satt] -> new state (wave wv: rows wv*16..+15) ----
      {
        f32x4 accp = zero;
        #pragma unroll
        for (int kc = 0; kc < 4; ++kc) {
          f16x8 ag = *(const f16x8*)&g2r[(size_t)(wv * 16 + l15) * HDIM + kc * 32 + l4 * 8];
          accp = MFMA(ag, We3f[kc], accp);
        }
        f16x8 ax = *(const f16x8*)&lds_x[wv * 16 + l15][l4 * 8];
        f32x4 acci = MFMA(ax, Winf, zero);
        #pragma unroll
        for (int i = 0; i < 4; ++i) {
          float rr = (l15 < 8) ? rrA[i] : rrB[i];
          float sa = (l15 < 8) ? saA[i] : saB[i];
          float ns = 0.7f * (sa + battr) + 0.3f * tanhf(acci[i] + rr + accp[i] + be3r);
          if (colvx) lds_ns[wv * 16 + l4 * 4 + i][l15] = (_Float16)ns;
        }
      }
      __syncthreads();
      if (tid < 64) {
        f16x8 vA = *(const f16x8*)&lds_ns[tid][0];
        stg16(&swrite[(size_t)tid * NRES + 8 * b], __builtin_bit_cast(f32x4, vA));
        if (dual) {
          f16x8 vB = *(const f16x8*)&lds_ns[tid][8];
          stg16(&swrite[(size_t)tid * NRES + 8 * (b - 4)], __builtin_bit_cast(f32x4, vB));
        }
      }
    }

    // ========== single global barrier per step (independent spin) ==========
    gbar5(slots, b, (unsigned)(t + 1));
  }

  // ---- Bayesian output head (blocks 0..63, post final barrier) ----
  if (b < BBATCH) {
    float* red = &lds_red[0][0][0];
    int o = tid >> 4, sg = tid & 15;
    float p = 0.f;
    for (int n = sg * 128; n < sg * 128 + 128; ++n) {
      float sv = (float)s16[(size_t)b * NRES + n];
      float w = w_mu[(size_t)o * NRES + n]
              + log1pf(expf(w_rho[(size_t)o * NRES + n])) * w_eps[(size_t)o * NRES + n];
      p += sv * w;
    }
    red[o * 17 + sg] = p;
    __syncthreads();
    if (tid < DOUT) {
      float sum = 0.f;
      for (int q = 0; q < 16; ++q) sum += red[tid * 17 + q];
      float bs = b_mu[tid] + log1pf(expf(b_rho[tid])) * b_eps[tid];
      out[b * DOUT + tid] = sum + bs;
    }
  }
}

// ---------------- host ----------------

extern "C" void kernel_launch(void* const* d_in, const int* in_sizes, int n_in,
                              void* d_out, int out_size, void* d_ws, size_t ws_size,
                              hipStream_t stream) {
  (void)in_sizes; (void)n_in; (void)out_size; (void)ws_size;
  const float* x     = (const float*)d_in[0];
  const float* W_in  = (const float*)d_in[1];
  const float* W_res = (const float*)d_in[2];
  const float* Wv    = (const float*)d_in[3];
  const float* bv    = (const float*)d_in[4];
  const float* Wproj = (const float*)d_in[5];
  const float* bproj = (const float*)d_in[6];
  const float* We1   = (const float*)d_in[7];
  const float* be1   = (const float*)d_in[8];
  const float* ln_g  = (const float*)d_in[9];
  const float* ln_b  = (const float*)d_in[10];
  const float* We2   = (const float*)d_in[11];
  const float* be2   = (const float*)d_in[12];
  const float* We3   = (const float*)d_in[13];
  const float* be3   = (const float*)d_in[14];
  const float* w_mu  = (const float*)d_in[15];
  const float* w_rho = (const float*)d_in[16];
  const float* b_mu  = (const float*)d_in[17];
  const float* b_rho = (const float*)d_in[18];
  const float* w_eps = (const float*)d_in[19];
  const float* b_eps = (const float*)d_in[20];
  float* out = (float*)d_out;

  char* ws = (char*)d_ws;
  _Float16* wpk      = (_Float16*)(ws + OFF_WPK);
  _Float16* wh1      = (_Float16*)(ws + OFF_WH1);
  float*    bias_big = (float*)(ws + OFF_BIAS);
  _Float16* we2h     = (_Float16*)(ws + OFF_WE2H);
  _Float16* we3h     = (_Float16*)(ws + OFF_WE3H);
  _Float16* winh     = (_Float16*)(ws + OFF_WINH);
  _Float16* g2buf    = (_Float16*)(ws + OFF_G2);
  unsigned* cnt      = (unsigned*)(ws + OFF_CNT);
  _Float16* s16      = (_Float16*)(ws + OFF_S16);

  hipMemsetAsync(bias_big, 0, 4224 * sizeof(float), stream);
  hipMemsetAsync(s16, 0, (size_t)S16N * sizeof(_Float16), stream);  // ring slot 0
  hipMemsetAsync(cnt, 0, (64 + 4096) * 4, stream);

  k_castres<<<2048, 256, 0, stream>>>(W_res, wpk);
  k_cast<<<64,   256, 0, stream>>>(We2, we2h, HDIM * HDIM);
  k_cast<<<1024, 256, 0, stream>>>(We3, we3h, NRES * HDIM);
  k_cast<<<256,  256, 0, stream>>>(W_in, winh, NRES * DIN);
  k_batt<<<NRES, 256, 0, stream>>>(Wproj, bv, bproj, bias_big);
  k_gemm1<<<dim3(32, 32), 256, 0, stream>>>(Wproj, Wv, wpk);
  k_bh1<<<HDIM, 256, 0, stream>>>(We1, be1, bias_big);
  k_gemm2<<<dim3(32, 2), 256, 0, stream>>>(We1, wpk, wh1);

  k_main<<<NBLK, 256, 0, stream>>>(x, ln_g, ln_b, be2, be3,
                                   w_mu, w_rho, b_mu, b_rho, w_eps, b_eps,
                                   wpk, wh1, bias_big, we2h, we3h, winh,
                                   s16, g2buf, cnt, out);
}